// Round 6
// baseline (1878.637 us; speedup 1.0000x reference)
//
#include <hip/hip_runtime.h>
#include <cstdint>
#include <cstddef>

// ---------------------------------------------------------------------------
// FeatureWiseCrossAttentionLSTM: F=40, OF=8, OW=24, L=3, H=128, NH=4, G=5
// B=32, T=512.
// R5b (compile fix of R5): kill the per-step vmcnt(0) barrier drain.
//   - L0: whole x slice (16b x 512t fp32 = 32 KB) preloaded to LDS once.
//   - L12: x staged in 4-step chunks via dbl-buffered LDS slab; global burst
//     once per 4 steps (held in regs one chunk, ds_write into idle slab).
//     Per-step x-fragments via ds_read_b128 (lgkm only).
//   - h-MFMA chain tree-split (2+2+add) to shorten the serial dep path.
//   - deferred (aged) global h-store kept from R4.
// ---------------------------------------------------------------------------

#define NFEAT 40
#define TDIM  512
#define HDIM  128

typedef __bf16 bf16x8 __attribute__((ext_vector_type(8)));
typedef float floatx4 __attribute__((ext_vector_type(4)));
typedef int   intx4   __attribute__((ext_vector_type(4)));
typedef unsigned short u16;

#if __has_builtin(__builtin_amdgcn_exp2f)
#define EXP2F __builtin_amdgcn_exp2f
#else
#define EXP2F exp2f
#endif
#if __has_builtin(__builtin_amdgcn_rcpf)
#define RCPF __builtin_amdgcn_rcpf
#else
#define RCPF(x) (1.f / (x))
#endif

#define MF(a, b, c) __builtin_amdgcn_mfma_f32_16x16x32_bf16( \
    __builtin_bit_cast(bf16x8, (a)), __builtin_bit_cast(bf16x8, (b)), (c), 0, 0, 0)

__device__ __forceinline__ float bf2f(u16 s) {
  union { unsigned u; float f; } v; v.u = ((unsigned)s) << 16; return v.f;
}
__device__ __forceinline__ unsigned f2bf(float f) {
  union { float f; unsigned u; } v; v.f = f;
  unsigned u = v.u + 0x7fffu + ((v.u >> 16) & 1u);
  return (u >> 16);
}

// ---------------------------------------------------------------------------
// prep: fp32->bf16 weight converts (native layouts) + combined bias.
// ---------------------------------------------------------------------------
__global__ void prep_kernel(const float* __restrict__ w_ih12,
                            const float* __restrict__ w_hh,
                            const float* __restrict__ b_ih,
                            const float* __restrict__ b_hh,
                            u16* __restrict__ Whh,
                            u16* __restrict__ Wih,
                            float* __restrict__ biasAll)
{
  const int N_hh = 3 * NFEAT * 512 * 128;
  const int N_ih = 2 * NFEAT * 512 * 128;
  const int NB   = 3 * NFEAT * 512;
  const int total = N_hh + N_ih + NB;
  for (int idx = blockIdx.x * blockDim.x + threadIdx.x; idx < total;
       idx += gridDim.x * blockDim.x) {
    if (idx < N_hh) {
      Whh[idx] = (u16)f2bf(w_hh[idx]);
    } else if (idx < N_hh + N_ih) {
      int i = idx - N_hh;
      Wih[i] = (u16)f2bf(w_ih12[i]);
    } else {
      int i = idx - N_hh - N_ih;
      biasAll[i] = b_ih[i] + b_hh[i];
    }
  }
}

// ---------------------------------------------------------------------------
// LSTM layer. Grid: 80 blocks = (f = bx>>1, half = bx&1). 512 threads.
// ---------------------------------------------------------------------------
template <bool IS_L0, bool IS_LAST>
__global__ __launch_bounds__(512, 2) void lstm_layer(
    const u16* __restrict__ Wh,      // [40][512][128] bf16 (this layer)
    const u16* __restrict__ Wx,      // [40][512][128] bf16 (L12; unused L0)
    const float* __restrict__ bias,  // [40][512] combined
    const float* __restrict__ xin,   // L0 only: x (B,F,T) fp32
    const float* __restrict__ w0,    // L0 only: w_ih0 (F,512) fp32
    u16* __restrict__ hseq)          // [40][512][32][128] bf16
{
  const int tid  = threadIdx.x;
  const int wave = tid >> 6;
  const int lane = tid & 63;
  const int m15  = lane & 15;          // batch (B-operand col / D col)
  const int q    = lane >> 4;          // quad
  const int kb   = q * 8;              // k offset within 32-chunk (u16)
  const int wq4  = wave * 16 + q * 4;  // first hidden col owned by lane
  const int f    = blockIdx.x >> 1;
  const int half = blockIdx.x & 1;

  const floatx4 FZ = {0.f, 0.f, 0.f, 0.f};

  __shared__ __align__(16) u16 A[2][16][136];                // h operand dbuf
  __shared__ __align__(16) u16 Xs12[IS_L0 ? 1 : 2*4*16*136]; // L12 x slab dbuf
  __shared__ float Xs0[IS_L0 ? TDIM * 16 : 1];               // L0 whole-x slab

#define XIDX(sl, row, b, k) (((((sl)*4 + (row))*16 + (b))*136) + (k))

  // ---- resident W_hh fragments (A-operand): rows g*128 + wave*16 + m15 ----
  intx4 whf[4][4];
  const size_t wbase = (size_t)f * 512 * 128;
#pragma unroll
  for (int g = 0; g < 4; ++g)
#pragma unroll
    for (int kt = 0; kt < 4; ++kt)
      whf[g][kt] = *(const intx4*)(Wh + wbase +
          (size_t)(g * 128 + wave * 16 + m15) * 128 + kt * 32 + kb);

  intx4 wxf[4][4];
  if constexpr (!IS_L0) {
#pragma unroll
    for (int g = 0; g < 4; ++g)
#pragma unroll
      for (int kt = 0; kt < 4; ++kt)
        wxf[g][kt] = *(const intx4*)(Wx + wbase +
            (size_t)(g * 128 + wave * 16 + m15) * 128 + kt * 32 + kb);
  }

  floatx4 bv[4], w0v[4];
#pragma unroll
  for (int g = 0; g < 4; ++g) {
    bv[g] = *(const floatx4*)(bias + f * 512 + g * 128 + wq4);
    if constexpr (IS_L0) w0v[g] = *(const floatx4*)(w0 + f * 512 + g * 128 + wq4);
  }

  // ---- zero A (h0 = 0) ----
  for (int idx = tid; idx < 2 * 16 * 136; idx += 512) ((u16*)A)[idx] = 0;

  // ---- prime x staging ----
  const char* gx = (const char*)hseq + (size_t)f * 4194304 + (size_t)half * 4096;
  intx4 sreg[2];   // held chunk (next) for L12
  if constexpr (!IS_L0) {
#pragma unroll
    for (int k2 = 0; k2 < 2; ++k2) {
      const int u = tid + k2 * 512;
      const int toff = u >> 8, rem = u & 255, b = rem >> 4, jc = rem & 15;
      // chunk 0 -> slab 0 (direct)
      intx4 v = *(const intx4*)(gx + (size_t)toff * 8192 + b * 256 + jc * 16);
      *(intx4*)&Xs12[XIDX(0, toff, b, jc * 8)] = v;
      // chunk 1 -> regs (written to slab 1 at t=0)
      sreg[k2] = *(const intx4*)(gx + (size_t)(4 + toff) * 8192 + b * 256 + jc * 16);
    }
  } else {
    const float* xg = xin + ((size_t)(half * 16) * NFEAT + f) * 512;
#pragma unroll
    for (int k2 = 0; k2 < 16; ++k2)
      Xs0[tid * 16 + k2] = xg[(size_t)k2 * (NFEAT * 512) + tid];
  }
  __syncthreads();

  // ---- C-init for t=0: bias + Wx*x(0) (or rank-1 for L0) ----
  floatx4 acc_c[4];
  if constexpr (!IS_L0) {
    intx4 xf[4];
#pragma unroll
    for (int kt = 0; kt < 4; ++kt)
      xf[kt] = *(const intx4*)&Xs12[XIDX(0, 0, m15, kt * 32 + kb)];
#pragma unroll
    for (int g = 0; g < 4; ++g) {
      floatx4 a = bv[g];
#pragma unroll
      for (int kt = 0; kt < 4; ++kt) a = MF(wxf[g][kt], xf[kt], a);
      acc_c[g] = a;
    }
  } else {
    const float x0 = Xs0[0 * 16 + m15];
#pragma unroll
    for (int g = 0; g < 4; ++g) acc_c[g] = bv[g] + w0v[g] * x0;
  }

  float creg[4] = {0.f, 0.f, 0.f, 0.f};
  u16* hwr = hseq + (size_t)f * (512 * 4096) +
             (size_t)(half * 16 + m15) * 128 + wq4;   // slot t=0
  uint2 hdef;

#define LSTM_STEP(P, DO_STAGE, T)                                              \
  {                                                                            \
    /* deferred (aged) global h-store from previous step */                    \
    if constexpr (!IS_LAST) {                                                  \
      if ((T) > 0) *(uint2*)(hwr - 4096) = hdef;                               \
    }                                                                          \
    /* chunk staging: once per 4 steps, L12 only */                            \
    if constexpr (!IS_L0) {                                                    \
      if (DO_STAGE) {                                                          \
        const int sl = (((T) >> 2) + 1) & 1;                                   \
        _Pragma("unroll")                                                      \
        for (int k2 = 0; k2 < 2; ++k2) {                                       \
          const int u = tid + k2 * 512;                                        \
          const int toff = u >> 8, rem = u & 255, b = rem >> 4, jc = rem & 15; \
          *(intx4*)&Xs12[XIDX(sl, toff, b, jc * 8)] = sreg[k2];                \
        }                                                                      \
        const int t0 = (T) + 8;                                                \
        _Pragma("unroll")                                                      \
        for (int k2 = 0; k2 < 2; ++k2) {                                       \
          const int u = tid + k2 * 512;                                        \
          const int toff = u >> 8, rem = u & 255, b = rem >> 4, jc = rem & 15; \
          const int tc = (t0 + toff < TDIM) ? t0 + toff : TDIM - 1;            \
          sreg[k2] = *(const intx4*)(gx + (size_t)tc * 8192 + b * 256 + jc * 16); \
        }                                                                      \
      }                                                                        \
    }                                                                          \
    /* h fragments from LDS */                                                 \
    intx4 hf0 = *(const intx4*)&A[P][m15][kb];                                 \
    intx4 hf1 = *(const intx4*)&A[P][m15][32 + kb];                            \
    intx4 hf2 = *(const intx4*)&A[P][m15][64 + kb];                            \
    intx4 hf3 = *(const intx4*)&A[P][m15][96 + kb];                            \
    /* x fragments / scalar for t+1 */                                         \
    const int tt = ((T) + 1 < TDIM) ? (T) + 1 : TDIM - 1;                      \
    intx4 xf0, xf1, xf2, xf3;                                                  \
    float xsv = 0.f;                                                           \
    if constexpr (!IS_L0) {                                                    \
      const int sl = (tt >> 2) & 1, row = tt & 3;                              \
      xf0 = *(const intx4*)&Xs12[XIDX(sl, row, m15, kb)];                      \
      xf1 = *(const intx4*)&Xs12[XIDX(sl, row, m15, 32 + kb)];                 \
      xf2 = *(const intx4*)&Xs12[XIDX(sl, row, m15, 64 + kb)];                 \
      xf3 = *(const intx4*)&Xs12[XIDX(sl, row, m15, 96 + kb)];                 \
    } else {                                                                   \
      xsv = Xs0[tt * 16 + m15];                                                \
    }                                                                          \
    /* h-MFMA, tree-split (2+2): chain A from acc_c (bias+x), chain B from 0 */\
    floatx4 ac[4];                                                             \
    _Pragma("unroll")                                                          \
    for (int g = 0; g < 4; ++g) {                                              \
      floatx4 ph = MF(whf[g][0], hf0, acc_c[g]);                               \
      ph = MF(whf[g][1], hf1, ph);                                             \
      floatx4 qh = MF(whf[g][2], hf2, FZ);                                     \
      qh = MF(whf[g][3], hf3, qh);                                             \
      ac[g] = ph + qh;                                                         \
    }                                                                          \
    /* x-group: NEXT step's C-init, overwrites acc_c (off critical path) */    \
    if constexpr (!IS_L0) {                                                    \
      _Pragma("unroll")                                                        \
      for (int g = 0; g < 4; ++g) {                                            \
        floatx4 n = bv[g];                                                     \
        n = MF(wxf[g][0], xf0, n);                                             \
        n = MF(wxf[g][1], xf1, n);                                             \
        n = MF(wxf[g][2], xf2, n);                                             \
        n = MF(wxf[g][3], xf3, n);                                             \
        acc_c[g] = n;                                                          \
      }                                                                        \
    } else {                                                                   \
      _Pragma("unroll")                                                        \
      for (int g = 0; g < 4; ++g) acc_c[g] = bv[g] + w0v[g] * xsv;             \
    }                                                                          \
    /* epilogue: lane owns (batch m15, j = wq4 + r) */                         \
    unsigned hlo, hhi;                                                         \
    {                                                                          \
      float hv[4];                                                             \
      _Pragma("unroll")                                                        \
      for (int r = 0; r < 4; ++r) {                                            \
        const float gi = ac[0][r], gf = ac[1][r], gg = ac[2][r], go = ac[3][r];\
        const float si = RCPF(1.f + EXP2F(-1.44269504f * gi));                 \
        const float sf = RCPF(1.f + EXP2F(-1.44269504f * gf));                 \
        const float so = RCPF(1.f + EXP2F(-1.44269504f * go));                 \
        const float tg = 2.f * RCPF(1.f + EXP2F(-2.88539008f * gg)) - 1.f;     \
        const float c  = sf * creg[r] + si * tg;                               \
        creg[r] = c;                                                           \
        const float th = 2.f * RCPF(1.f + EXP2F(-2.88539008f * c)) - 1.f;      \
        hv[r] = so * th;                                                       \
      }                                                                        \
      hlo = (f2bf(hv[1]) << 16) | f2bf(hv[0]);                                 \
      hhi = (f2bf(hv[3]) << 16) | f2bf(hv[2]);                                 \
    }                                                                          \
    uint2 hp; hp.x = hlo; hp.y = hhi;                                          \
    *(uint2*)&A[(P) ^ 1][m15][wq4] = hp;                                       \
    hdef = hp;                                                                 \
    hwr += 4096;                                                               \
    __syncthreads();                                                           \
  }

#pragma unroll 1
  for (int c = 0; c < TDIM / 4; ++c) {
    const int t = c * 4;
    LSTM_STEP(0, true,  t);
    LSTM_STEP(1, false, t + 1);
    LSTM_STEP(0, false, t + 2);
    LSTM_STEP(1, false, t + 3);
  }
#undef LSTM_STEP
#undef XIDX

  // final h (t = 511) store for all layer variants
  *(uint2*)(hwr - 4096) = hdef;
}

// ---------------------------------------------------------------------------
// Group attention: grid (G=5 x B=32) blocks, 128 threads.
// ---------------------------------------------------------------------------
__global__ void gattn_kernel(const u16* __restrict__ hseq,
                             const float* __restrict__ g_wqkv,
                             const float* __restrict__ g_bqkv,
                             const float* __restrict__ g_wo,
                             const float* __restrict__ g_bo,
                             float* __restrict__ pooled)
{
  const int tid = threadIdx.x;
  const int g = blockIdx.x >> 5;
  const int b = blockIdx.x & 31;

  __shared__ float feat[8][128];
  __shared__ float qkv[8][384];
  __shared__ float sc[4][8][8];
  __shared__ float colsum[4][8];
  __shared__ float poolin[128];

  for (int idx = tid; idx < 8 * 128; idx += 128) {
    int of = idx >> 7, j = idx & 127;
    int f = g * 8 + of;
    feat[of][j] = bf2f(hseq[(((size_t)f * TDIM + (TDIM - 1)) * 32 + b) * 128 + j]);
  }
  __syncthreads();
  for (int idx = tid; idx < 8 * 384; idx += 128) {
    int of = idx / 384, r = idx - of * 384;
    const float* wr = g_wqkv + ((size_t)g * 384 + r) * 128;
    float s = 0.f;
    for (int j = 0; j < 128; ++j) s += feat[of][j] * wr[j];
    qkv[of][r] = s + g_bqkv[g * 384 + r];
  }
  __syncthreads();
  for (int idx = tid; idx < 256; idx += 128) {
    int n = idx >> 6, qp = (idx >> 3) & 7, kp = idx & 7;
    float s = 0.f;
    for (int d = 0; d < 32; ++d)
      s += qkv[qp][n * 32 + d] * qkv[kp][128 + n * 32 + d];
    sc[n][qp][kp] = s * 0.17677669529663687f;
  }
  __syncthreads();
  if (tid < 32) {
    int n = tid >> 3, qp = tid & 7;
    float mx = -1e30f;
    for (int kp = 0; kp < 8; ++kp) mx = fmaxf(mx, sc[n][qp][kp]);
    float e[8], sum = 0.f;
    for (int kp = 0; kp < 8; ++kp) { e[kp] = __expf(sc[n][qp][kp] - mx); sum += e[kp]; }
    float inv = 1.f / sum;
    for (int kp = 0; kp < 8; ++kp) sc[n][qp][kp] = e[kp] * inv;
  }
  __syncthreads();
  if (tid < 32) {
    int n = tid >> 3, kp = tid & 7;
    float s = 0.f;
    for (int qp = 0; qp < 8; ++qp) s += sc[n][qp][kp];
    colsum[n][kp] = s;
  }
  __syncthreads();
  {
    int n = tid >> 5;
    float s = 0.f;
    for (int kp = 0; kp < 8; ++kp) s += colsum[n][kp] * qkv[kp][256 + tid];
    poolin[tid] = s;
  }
  __syncthreads();
  {
    const float* wr = g_wo + ((size_t)g * 128 + tid) * 128;
    float s = 0.f;
    for (int i = 0; i < 128; ++i) s += poolin[i] * wr[i];
    pooled[((size_t)b * 5 + g) * 128 + tid] = s * 0.125f + g_bo[g * 128 + tid];
  }
}

// ---------------------------------------------------------------------------
// Final attention (query pos 0 only) + FC. Grid: 32 blocks, 192 threads.
// ---------------------------------------------------------------------------
__global__ void final_kernel(const float* __restrict__ pooled,
                             const float* __restrict__ f_wqkv,
                             const float* __restrict__ f_bqkv,
                             const float* __restrict__ f_wo,
                             const float* __restrict__ f_bo,
                             const float* __restrict__ fc_w,
                             const float* __restrict__ fc_b,
                             float* __restrict__ out)
{
  const int tid = threadIdx.x;
  const int b = blockIdx.x;

  __shared__ float P[5][128];
  __shared__ float q0[128];
  __shared__ float kbuf[5][128];
  __shared__ float vbuf[5][128];
  __shared__ float attn[4][5];
  __shared__ float ao[128];
  __shared__ float fin[128];

  for (int idx = tid; idx < 640; idx += 192) {
    int g = idx >> 7, j = idx & 127;
    P[g][j] = pooled[((size_t)b * 5 + g) * 128 + j];
  }
  __syncthreads();
  for (int idx = tid; idx < 1408; idx += 192) {
    int kind, pos, r;
    if (idx < 128)       { kind = 0; pos = 0;                 r = idx; }
    else if (idx < 768)  { kind = 1; pos = (idx - 128) >> 7;  r = (idx - 128) & 127; }
    else                 { kind = 2; pos = (idx - 768) >> 7;  r = (idx - 768) & 127; }
    const int wrow = kind * 128 + r;
    const float* wr = f_wqkv + (size_t)wrow * 128;
    const float* src = P[kind == 0 ? 0 : pos];
    float s = 0.f;
    for (int j = 0; j < 128; ++j) s += src[j] * wr[j];
    s += f_bqkv[wrow];
    if (kind == 0) q0[r] = s;
    else if (kind == 1) kbuf[pos][r] = s;
    else vbuf[pos][r] = s;
  }
  __syncthreads();
  if (tid < 20) {
    int n = tid / 5, kp = tid - n * 5;
    float s = 0.f;
    for (int d = 0; d < 32; ++d) s += q0[n * 32 + d] * kbuf[kp][n * 32 + d];
    attn[n][kp] = s * 0.17677669529663687f;
  }
  __syncthreads();
  if (tid < 4) {
    float mx = -1e30f;
    for (int kp = 0; kp < 5; ++kp) mx = fmaxf(mx, attn[tid][kp]);
    float sum = 0.f;
    for (int kp = 0; kp < 5; ++kp) { float e = __expf(attn[tid][kp] - mx); attn[tid][kp] = e; sum += e; }
    float inv = 1.f / sum;
    for (int kp = 0; kp < 5; ++kp) attn[tid][kp] *= inv;
  }
  __syncthreads();
  if (tid < 128) {
    int n = tid >> 5;
    float s = 0.f;
    for (int kp = 0; kp < 5; ++kp) s += attn[n][kp] * vbuf[kp][tid];
    ao[tid] = s;
  }
  __syncthreads();
  if (tid < 128) {
    const float* wr = f_wo + (size_t)tid * 128;
    float s = 0.f;
    for (int i = 0; i < 128; ++i) s += ao[i] * wr[i];
    fin[tid] = s + f_bo[tid];
  }
  __syncthreads();
  {
    const float* wr = fc_w + (size_t)tid * 128;
    float s = 0.f;
    for (int j = 0; j < 128; ++j) s += fin[j] * wr[j];
    out[(size_t)b * 192 + tid] = s + fc_b[tid];
  }
}

// ---------------------------------------------------------------------------
extern "C" void kernel_launch(void* const* d_in, const int* in_sizes, int n_in,
                              void* d_out, int out_size, void* d_ws, size_t ws_size,
                              hipStream_t stream)
{
  const float* x      = (const float*)d_in[0];
  const float* w_ih0  = (const float*)d_in[1];
  const float* w_ih12 = (const float*)d_in[2];
  const float* w_hh   = (const float*)d_in[3];
  const float* b_ih   = (const float*)d_in[4];
  const float* b_hh   = (const float*)d_in[5];
  const float* g_wqkv = (const float*)d_in[6];
  const float* g_bqkv = (const float*)d_in[7];
  const float* g_wo   = (const float*)d_in[8];
  const float* g_bo   = (const float*)d_in[9];
  const float* f_wqkv = (const float*)d_in[10];
  const float* f_bqkv = (const float*)d_in[11];
  const float* f_wo   = (const float*)d_in[12];
  const float* f_bo   = (const float*)d_in[13];
  const float* fc_w   = (const float*)d_in[14];
  const float* fc_b   = (const float*)d_in[15];

  const size_t N_hh = (size_t)3 * NFEAT * 512 * 128;
  const size_t N_ih = (size_t)2 * NFEAT * 512 * 128;
  const size_t NB   = (size_t)3 * NFEAT * 512;
  const size_t LSL  = (size_t)NFEAT * 512 * 128;

  u16* Whh       = (u16*)d_ws;
  u16* Wih       = Whh + N_hh;
  float* biasAll = (float*)(Wih + N_ih);
  u16* hseq      = (u16*)(biasAll + NB);
  float* pooled  = (float*)(hseq + (size_t)NFEAT * TDIM * 32 * 128);

  prep_kernel<<<2048, 256, 0, stream>>>(w_ih12, w_hh, b_ih, b_hh, Whh, Wih, biasAll);

  lstm_layer<true, false><<<80, 512, 0, stream>>>(
      Whh, Whh /*unused*/, biasAll, x, w_ih0, hseq);
  lstm_layer<false, false><<<80, 512, 0, stream>>>(
      Whh + LSL, Wih, biasAll + NFEAT * 512, nullptr, nullptr, hseq);
  lstm_layer<false, true><<<80, 512, 0, stream>>>(
      Whh + 2 * LSL, Wih + LSL, biasAll + 2 * NFEAT * 512, nullptr, nullptr, hseq);

  gattn_kernel<<<160, 128, 0, stream>>>(hseq, g_wqkv, g_bqkv, g_wo, g_bo, pooled);
  final_kernel<<<32, 192, 0, stream>>>(pooled, f_wqkv, f_bqkv, f_wo, f_bo,
                                       fc_w, fc_b, (float*)d_out);
}

// Round 7
// 1057.884 us; speedup vs baseline: 1.7758x; 1.7758x over previous
//
#include <hip/hip_runtime.h>
#include <cstdint>
#include <cstddef>

// ---------------------------------------------------------------------------
// FeatureWiseCrossAttentionLSTM: F=40, OF=8, OW=24, L=3, H=128, NH=4, G=5
// B=32, T=512.
// R6: cross-layer pipelining. R5b falsified the barrier-drain theory (removing
// all per-step global loads changed nothing); active CUs are ~issue-bound
// (VALUBusy 58% + trans floor 640cyc/step/CU) with 176 CUs idle. So: ONE
// 240-block kernel; layer l blocks consume layer l-1's h stream ~15 steps
// behind through 256-step rings + device-scope flags.
//   - producer h-stores: 64-bit agent-scope atomic stores (cross-XCD coherent)
//   - producer publishes flag=T-1 every 8 steps (threadfence + atomic store)
//   - consumer polls once per 8-step chunk (spin + threadfence acquire-inv),
//     x-prefetch 3 steps ahead as in R4 (best-known step body, kept verbatim)
//   - serial span: 3*512 -> ~512+2*15 steps.
// ---------------------------------------------------------------------------

#define NFEAT 40
#define TDIM  512

typedef __bf16 bf16x8 __attribute__((ext_vector_type(8)));
typedef float floatx4 __attribute__((ext_vector_type(4)));
typedef int   intx4   __attribute__((ext_vector_type(4)));
typedef unsigned short u16;
typedef unsigned long long u64;

#if __has_builtin(__builtin_amdgcn_exp2f)
#define EXP2F __builtin_amdgcn_exp2f
#else
#define EXP2F exp2f
#endif
#if __has_builtin(__builtin_amdgcn_rcpf)
#define RCPF __builtin_amdgcn_rcpf
#else
#define RCPF(x) (1.f / (x))
#endif

#define MF(a, b, c) __builtin_amdgcn_mfma_f32_16x16x32_bf16( \
    __builtin_bit_cast(bf16x8, (a)), __builtin_bit_cast(bf16x8, (b)), (c), 0, 0, 0)

__device__ __forceinline__ float bf2f(u16 s) {
  union { unsigned u; float f; } v; v.u = ((unsigned)s) << 16; return v.f;
}
__device__ __forceinline__ unsigned f2bf(float f) {
  union { float f; unsigned u; } v; v.f = f;
  unsigned u = v.u + 0x7fffu + ((v.u >> 16) & 1u);
  return (u >> 16);
}

// ring geometry (per layer-boundary): [40][256][32][128] bf16
#define RING_FSTRIDE 1048576   // 256*4096 u16
#define RING_TSTRIDE 4096      // 32*128 u16
#define RING_MASK    255

// ---------------------------------------------------------------------------
// prep: fp32->bf16 weight converts + combined bias + ZERO the sync flags.
// ---------------------------------------------------------------------------
__global__ void prep_kernel(const float* __restrict__ w_ih12,
                            const float* __restrict__ w_hh,
                            const float* __restrict__ b_ih,
                            const float* __restrict__ b_hh,
                            u16* __restrict__ Whh,
                            u16* __restrict__ Wih,
                            float* __restrict__ biasAll,
                            int* __restrict__ flags)
{
  const int N_hh = 3 * NFEAT * 512 * 128;
  const int N_ih = 2 * NFEAT * 512 * 128;
  const int NB   = 3 * NFEAT * 512;
  const int NF   = 192;   // 160 flags, padded
  const int total = N_hh + N_ih + NB + NF;
  for (int idx = blockIdx.x * blockDim.x + threadIdx.x; idx < total;
       idx += gridDim.x * blockDim.x) {
    if (idx < N_hh) {
      Whh[idx] = (u16)f2bf(w_hh[idx]);
    } else if (idx < N_hh + N_ih) {
      int i = idx - N_hh;
      Wih[i] = (u16)f2bf(w_ih12[i]);
    } else if (idx < N_hh + N_ih + NB) {
      int i = idx - N_hh - N_ih;
      biasAll[i] = b_ih[i] + b_hh[i];
    } else {
      flags[idx - N_hh - N_ih - NB] = 0;
    }
  }
}

// ---------------------------------------------------------------------------
// One layer's recurrence, R4 step body + ring/flag sync.
// ---------------------------------------------------------------------------
template <int LAYER>
__device__ __forceinline__ void lstm_body(
    const u16* __restrict__ Wh, const u16* __restrict__ Wx,
    const float* __restrict__ bias,
    const float* __restrict__ xin, const float* __restrict__ w0,
    const u16* __restrict__ ringIn, u16* __restrict__ ringOut,
    u16* __restrict__ hlast,
    int* __restrict__ flagIn, int* __restrict__ flagOut,
    int f, int half, u16* __restrict__ Abase)
{
  constexpr bool IS_L0   = (LAYER == 0);
  constexpr bool IS_LAST = (LAYER == 2);

  const int tid  = threadIdx.x;
  const int wave = tid >> 6;
  const int lane = tid & 63;
  const int m15  = lane & 15;          // batch (B-col / D-col)
  const int q    = lane >> 4;
  const int kb   = q * 8;
  const int wq4  = wave * 16 + q * 4;  // first hidden col owned by lane

#define ALDS(P, M, K) (Abase + ((P) * 16 + (M)) * 136 + (K))

  // ---- resident weight fragments ----
  intx4 whf[4][4];
  const size_t wbase = (size_t)f * 512 * 128;
#pragma unroll
  for (int g = 0; g < 4; ++g)
#pragma unroll
    for (int kt = 0; kt < 4; ++kt)
      whf[g][kt] = *(const intx4*)(Wh + wbase +
          (size_t)(g * 128 + wave * 16 + m15) * 128 + kt * 32 + kb);

  intx4 wxf[4][4];
  if constexpr (!IS_L0) {
#pragma unroll
    for (int g = 0; g < 4; ++g)
#pragma unroll
      for (int kt = 0; kt < 4; ++kt)
        wxf[g][kt] = *(const intx4*)(Wx + wbase +
            (size_t)(g * 128 + wave * 16 + m15) * 128 + kt * 32 + kb);
  }

  floatx4 bv[4], w0v[4];
#pragma unroll
  for (int g = 0; g < 4; ++g) {
    bv[g] = *(const floatx4*)(bias + f * 512 + g * 128 + wq4);
    if constexpr (IS_L0) w0v[g] = *(const floatx4*)(w0 + f * 512 + g * 128 + wq4);
  }

  // ---- zero A (h0 = 0) ----
  for (int idx = tid; idx < 2 * 16 * 136; idx += 512) Abase[idx] = 0;

  // ---- initial poll: need x_0..x_10 before priming + first chunk ----
  if constexpr (LAYER >= 1) {
    if (tid == 0) {
      while (__hip_atomic_load(flagIn, __ATOMIC_RELAXED,
                               __HIP_MEMORY_SCOPE_AGENT) < 11)
        __builtin_amdgcn_s_sleep(2);
      __threadfence();
    }
  }
  __syncthreads();

  // ---- prime x pipeline (R4 form, ring addressing) ----
  const u16* xbase = (LAYER >= 1)
      ? ringIn + (size_t)f * RING_FSTRIDE + (half * 16 + m15) * 128 + kb
      : nullptr;
  const float* xsbase = IS_L0
      ? xin + ((size_t)(half * 16 + m15) * NFEAT + f) * 512
      : nullptr;

  floatx4 accx0[4], accx1[4];
  intx4 xf0[4], xf1[4];
  float xsc[2] = {0.f, 0.f};

  if constexpr (!IS_L0) {
    intx4 p0[4];
#pragma unroll
    for (int kt = 0; kt < 4; ++kt) p0[kt]  = *(const intx4*)(xbase + kt * 32);
#pragma unroll
    for (int kt = 0; kt < 4; ++kt)
      xf0[kt] = *(const intx4*)(xbase + 1 * RING_TSTRIDE + kt * 32);
#pragma unroll
    for (int kt = 0; kt < 4; ++kt)
      xf1[kt] = *(const intx4*)(xbase + 2 * RING_TSTRIDE + kt * 32);
#pragma unroll
    for (int g = 0; g < 4; ++g) {
      floatx4 a = bv[g];
#pragma unroll
      for (int kt = 0; kt < 4; ++kt) a = MF(wxf[g][kt], p0[kt], a);
      accx0[g] = a;
    }
  } else {
    const float x0 = xsbase[0];
    xsc[0] = xsbase[1];
    xsc[1] = xsbase[2];
#pragma unroll
    for (int g = 0; g < 4; ++g) accx0[g] = bv[g] + w0v[g] * x0;
  }

  float creg[4] = {0.f, 0.f, 0.f, 0.f};
  u16* hb_ring = (LAYER <= 1)
      ? ringOut + (size_t)f * RING_FSTRIDE + (half * 16 + m15) * 128 + wq4
      : nullptr;
  u64 hdef64 = 0;

#define LSTM_STEP(PC, ACC_C, ACC_N, XF_C, T)                                   \
  {                                                                            \
    /* sync block: once per 8 steps */                                         \
    if (((T) & 7) == 0 && (T) > 0) {                                           \
      if (tid == 0) {                                                          \
        if constexpr (LAYER <= 1)                                              \
          __hip_atomic_store(flagOut, (T) - 1, __ATOMIC_RELAXED,               \
                             __HIP_MEMORY_SCOPE_AGENT);                        \
        if constexpr (LAYER >= 1) {                                            \
          int tgt = (T) + 11; if (tgt > 512) tgt = 512;                        \
          while (__hip_atomic_load(flagIn, __ATOMIC_RELAXED,                   \
                                   __HIP_MEMORY_SCOPE_AGENT) < tgt)            \
            __builtin_amdgcn_s_sleep(2);                                       \
        }                                                                      \
        __threadfence();                                                       \
      }                                                                        \
      if constexpr (LAYER >= 1) __syncthreads();                               \
    }                                                                          \
    /* deferred (aged) coherent h-store of h_{T-1} */                          \
    if constexpr (!IS_LAST) {                                                  \
      if ((T) > 0)                                                             \
        __hip_atomic_store(                                                    \
            (u64*)(hb_ring + (size_t)(((T) - 1) & RING_MASK) * RING_TSTRIDE),  \
            hdef64, __ATOMIC_RELAXED, __HIP_MEMORY_SCOPE_AGENT);               \
    }                                                                          \
    /* x prefetch for t+3 into temps */                                        \
    intx4 xn0, xn1, xn2, xn3;                                                  \
    float xns = 0.f;                                                           \
    {                                                                          \
      const int tl = ((T) + 3 < TDIM) ? (T) + 3 : TDIM - 1;                    \
      if constexpr (!IS_L0) {                                                  \
        const u16* xp = xbase + (size_t)(tl & RING_MASK) * RING_TSTRIDE;       \
        xn0 = *(const intx4*)(xp);                                             \
        xn1 = *(const intx4*)(xp + 32);                                        \
        xn2 = *(const intx4*)(xp + 64);                                        \
        xn3 = *(const intx4*)(xp + 96);                                        \
      } else {                                                                 \
        xns = xsbase[tl];                                                      \
      }                                                                        \
    }                                                                          \
    /* h fragments from LDS */                                                 \
    intx4 hf0 = *(const intx4*)ALDS(PC, m15, kb);                              \
    intx4 hf1 = *(const intx4*)ALDS(PC, m15, 32 + kb);                         \
    intx4 hf2 = *(const intx4*)ALDS(PC, m15, 64 + kb);                         \
    intx4 hf3 = *(const intx4*)ALDS(PC, m15, 96 + kb);                         \
    /* h-MFMA (critical path) */                                               \
    floatx4 ac0 = MF(whf[0][0], hf0, ACC_C[0]);                                \
    floatx4 ac1 = MF(whf[1][0], hf0, ACC_C[1]);                                \
    floatx4 ac2 = MF(whf[2][0], hf0, ACC_C[2]);                                \
    floatx4 ac3 = MF(whf[3][0], hf0, ACC_C[3]);                                \
    ac0 = MF(whf[0][1], hf1, ac0); ac1 = MF(whf[1][1], hf1, ac1);              \
    ac2 = MF(whf[2][1], hf1, ac2); ac3 = MF(whf[3][1], hf1, ac3);              \
    ac0 = MF(whf[0][2], hf2, ac0); ac1 = MF(whf[1][2], hf2, ac1);              \
    ac2 = MF(whf[2][2], hf2, ac2); ac3 = MF(whf[3][2], hf2, ac3);              \
    ac0 = MF(whf[0][3], hf3, ac0); ac1 = MF(whf[1][3], hf3, ac1);              \
    ac2 = MF(whf[2][3], hf3, ac2); ac3 = MF(whf[3][3], hf3, ac3);              \
    /* x-group: NEXT step's C-init (off critical path), then rotate */         \
    if constexpr (!IS_L0) {                                                    \
      floatx4 n0 = bv[0], n1 = bv[1], n2 = bv[2], n3 = bv[3];                  \
      n0 = MF(wxf[0][0], XF_C[0], n0); n1 = MF(wxf[1][0], XF_C[0], n1);        \
      n2 = MF(wxf[2][0], XF_C[0], n2); n3 = MF(wxf[3][0], XF_C[0], n3);        \
      n0 = MF(wxf[0][1], XF_C[1], n0); n1 = MF(wxf[1][1], XF_C[1], n1);        \
      n2 = MF(wxf[2][1], XF_C[1], n2); n3 = MF(wxf[3][1], XF_C[1], n3);        \
      n0 = MF(wxf[0][2], XF_C[2], n0); n1 = MF(wxf[1][2], XF_C[2], n1);        \
      n2 = MF(wxf[2][2], XF_C[2], n2); n3 = MF(wxf[3][2], XF_C[2], n3);        \
      n0 = MF(wxf[0][3], XF_C[3], n0); n1 = MF(wxf[1][3], XF_C[3], n1);        \
      n2 = MF(wxf[2][3], XF_C[3], n2); n3 = MF(wxf[3][3], XF_C[3], n3);        \
      ACC_N[0] = n0; ACC_N[1] = n1; ACC_N[2] = n2; ACC_N[3] = n3;              \
      XF_C[0] = xn0; XF_C[1] = xn1; XF_C[2] = xn2; XF_C[3] = xn3;              \
    } else {                                                                   \
      const float xn = xsc[PC];                                                \
      ACC_N[0] = bv[0] + w0v[0] * xn; ACC_N[1] = bv[1] + w0v[1] * xn;          \
      ACC_N[2] = bv[2] + w0v[2] * xn; ACC_N[3] = bv[3] + w0v[3] * xn;          \
      xsc[PC] = xns;                                                           \
    }                                                                          \
    /* epilogue: lane owns (batch m15, j = wq4 + r) */                         \
    unsigned hlo, hhi;                                                         \
    {                                                                          \
      float hv[4];                                                             \
      _Pragma("unroll")                                                        \
      for (int r = 0; r < 4; ++r) {                                            \
        const float gi = ac0[r], gf = ac1[r], gg = ac2[r], go = ac3[r];        \
        const float si = RCPF(1.f + EXP2F(-1.44269504f * gi));                 \
        const float sf = RCPF(1.f + EXP2F(-1.44269504f * gf));                 \
        const float so = RCPF(1.f + EXP2F(-1.44269504f * go));                 \
        const float tg = 2.f * RCPF(1.f + EXP2F(-2.88539008f * gg)) - 1.f;     \
        const float c  = sf * creg[r] + si * tg;                               \
        creg[r] = c;                                                           \
        const float th = 2.f * RCPF(1.f + EXP2F(-2.88539008f * c)) - 1.f;      \
        hv[r] = so * th;                                                       \
      }                                                                        \
      hlo = (f2bf(hv[1]) << 16) | f2bf(hv[0]);                                 \
      hhi = (f2bf(hv[3]) << 16) | f2bf(hv[2]);                                 \
    }                                                                          \
    uint2 hp; hp.x = hlo; hp.y = hhi;                                          \
    *(uint2*)ALDS((PC) ^ 1, m15, wq4) = hp;                                    \
    hdef64 = ((u64)hhi << 32) | (u64)hlo;                                      \
    __syncthreads();                                                           \
  }

#pragma unroll 1
  for (int t = 0; t < TDIM; t += 2) {
    LSTM_STEP(0, accx0, accx1, xf0, t);
    LSTM_STEP(1, accx1, accx0, xf1, t + 1);
  }
#undef LSTM_STEP
#undef ALDS

  // ---- tail: final h (t=511) ----
  if constexpr (!IS_LAST) {
    __hip_atomic_store((u64*)(hb_ring + (size_t)255 * RING_TSTRIDE), hdef64,
                       __ATOMIC_RELAXED, __HIP_MEMORY_SCOPE_AGENT);
    __syncthreads();   // drains the store (vmcnt) for every wave
    if (tid == 0) {
      __threadfence();
      __hip_atomic_store(flagOut, 512, __ATOMIC_RELAXED,
                         __HIP_MEMORY_SCOPE_AGENT);
    }
  } else {
    uint2 hp;
    hp.x = (unsigned)(hdef64 & 0xffffffffull);
    hp.y = (unsigned)(hdef64 >> 32);
    *(uint2*)(hlast + ((size_t)f * 32 + half * 16 + m15) * 128 + wq4) = hp;
  }
}

// ---------------------------------------------------------------------------
// Fused 3-layer LSTM: 240 blocks (80 per layer), all co-resident.
// ---------------------------------------------------------------------------
__global__ __launch_bounds__(512, 2) void lstm_fused(
    const u16* __restrict__ Whh, const u16* __restrict__ Wih,
    const float* __restrict__ biasAll,
    const float* __restrict__ xin, const float* __restrict__ w0,
    u16* __restrict__ ring0, u16* __restrict__ ring1,
    u16* __restrict__ hlast, int* __restrict__ flags)
{
  __shared__ __align__(16) u16 A[2 * 16 * 136];
  const int layer = blockIdx.x / 80;
  const int bx    = blockIdx.x % 80;
  const int f = bx >> 1, half = bx & 1;
  const size_t LSL = (size_t)NFEAT * 512 * 128;

  if (layer == 0) {
    lstm_body<0>(Whh, nullptr, biasAll, xin, w0,
                 nullptr, ring0, nullptr,
                 nullptr, flags + bx, f, half, A);
  } else if (layer == 1) {
    lstm_body<1>(Whh + LSL, Wih, biasAll + NFEAT * 512, nullptr, nullptr,
                 ring0, ring1, nullptr,
                 flags + bx, flags + 80 + bx, f, half, A);
  } else {
    lstm_body<2>(Whh + 2 * LSL, Wih + LSL, biasAll + 2 * NFEAT * 512,
                 nullptr, nullptr, ring1, nullptr, hlast,
                 flags + 80 + bx, nullptr, f, half, A);
  }
}

// ---------------------------------------------------------------------------
// Group attention: grid (G=5 x B=32) blocks, 128 threads.
// ---------------------------------------------------------------------------
__global__ void gattn_kernel(const u16* __restrict__ hlast,
                             const float* __restrict__ g_wqkv,
                             const float* __restrict__ g_bqkv,
                             const float* __restrict__ g_wo,
                             const float* __restrict__ g_bo,
                             float* __restrict__ pooled)
{
  const int tid = threadIdx.x;
  const int g = blockIdx.x >> 5;
  const int b = blockIdx.x & 31;

  __shared__ float feat[8][128];
  __shared__ float qkv[8][384];
  __shared__ float sc[4][8][8];
  __shared__ float colsum[4][8];
  __shared__ float poolin[128];

  for (int idx = tid; idx < 8 * 128; idx += 128) {
    int of = idx >> 7, j = idx & 127;
    int f = g * 8 + of;
    feat[of][j] = bf2f(hlast[((size_t)f * 32 + b) * 128 + j]);
  }
  __syncthreads();
  for (int idx = tid; idx < 8 * 384; idx += 128) {
    int of = idx / 384, r = idx - of * 384;
    const float* wr = g_wqkv + ((size_t)g * 384 + r) * 128;
    float s = 0.f;
    for (int j = 0; j < 128; ++j) s += feat[of][j] * wr[j];
    qkv[of][r] = s + g_bqkv[g * 384 + r];
  }
  __syncthreads();
  for (int idx = tid; idx < 256; idx += 128) {
    int n = idx >> 6, qp = (idx >> 3) & 7, kp = idx & 7;
    float s = 0.f;
    for (int d = 0; d < 32; ++d)
      s += qkv[qp][n * 32 + d] * qkv[kp][128 + n * 32 + d];
    sc[n][qp][kp] = s * 0.17677669529663687f;
  }
  __syncthreads();
  if (tid < 32) {
    int n = tid >> 3, qp = tid & 7;
    float mx = -1e30f;
    for (int kp = 0; kp < 8; ++kp) mx = fmaxf(mx, sc[n][qp][kp]);
    float e[8], sum = 0.f;
    for (int kp = 0; kp < 8; ++kp) { e[kp] = __expf(sc[n][qp][kp] - mx); sum += e[kp]; }
    float inv = 1.f / sum;
    for (int kp = 0; kp < 8; ++kp) sc[n][qp][kp] = e[kp] * inv;
  }
  __syncthreads();
  if (tid < 32) {
    int n = tid >> 3, kp = tid & 7;
    float s = 0.f;
    for (int qp = 0; qp < 8; ++qp) s += sc[n][qp][kp];
    colsum[n][kp] = s;
  }
  __syncthreads();
  {
    int n = tid >> 5;
    float s = 0.f;
    for (int kp = 0; kp < 8; ++kp) s += colsum[n][kp] * qkv[kp][256 + tid];
    poolin[tid] = s;
  }
  __syncthreads();
  {
    const float* wr = g_wo + ((size_t)g * 128 + tid) * 128;
    float s = 0.f;
    for (int i = 0; i < 128; ++i) s += poolin[i] * wr[i];
    pooled[((size_t)b * 5 + g) * 128 + tid] = s * 0.125f + g_bo[g * 128 + tid];
  }
}

// ---------------------------------------------------------------------------
// Final attention (query pos 0 only) + FC. Grid: 32 blocks, 192 threads.
// ---------------------------------------------------------------------------
__global__ void final_kernel(const float* __restrict__ pooled,
                             const float* __restrict__ f_wqkv,
                             const float* __restrict__ f_bqkv,
                             const float* __restrict__ f_wo,
                             const float* __restrict__ f_bo,
                             const float* __restrict__ fc_w,
                             const float* __restrict__ fc_b,
                             float* __restrict__ out)
{
  const int tid = threadIdx.x;
  const int b = blockIdx.x;

  __shared__ float P[5][128];
  __shared__ float q0[128];
  __shared__ float kbuf[5][128];
  __shared__ float vbuf[5][128];
  __shared__ float attn[4][5];
  __shared__ float ao[128];
  __shared__ float fin[128];

  for (int idx = tid; idx < 640; idx += 192) {
    int g = idx >> 7, j = idx & 127;
    P[g][j] = pooled[((size_t)b * 5 + g) * 128 + j];
  }
  __syncthreads();
  for (int idx = tid; idx < 1408; idx += 192) {
    int kind, pos, r;
    if (idx < 128)       { kind = 0; pos = 0;                 r = idx; }
    else if (idx < 768)  { kind = 1; pos = (idx - 128) >> 7;  r = (idx - 128) & 127; }
    else                 { kind = 2; pos = (idx - 768) >> 7;  r = (idx - 768) & 127; }
    const int wrow = kind * 128 + r;
    const float* wr = f_wqkv + (size_t)wrow * 128;
    const float* src = P[kind == 0 ? 0 : pos];
    float s = 0.f;
    for (int j = 0; j < 128; ++j) s += src[j] * wr[j];
    s += f_bqkv[wrow];
    if (kind == 0) q0[r] = s;
    else if (kind == 1) kbuf[pos][r] = s;
    else vbuf[pos][r] = s;
  }
  __syncthreads();
  if (tid < 20) {
    int n = tid / 5, kp = tid - n * 5;
    float s = 0.f;
    for (int d = 0; d < 32; ++d) s += q0[n * 32 + d] * kbuf[kp][n * 32 + d];
    attn[n][kp] = s * 0.17677669529663687f;
  }
  __syncthreads();
  if (tid < 4) {
    float mx = -1e30f;
    for (int kp = 0; kp < 5; ++kp) mx = fmaxf(mx, attn[tid][kp]);
    float sum = 0.f;
    for (int kp = 0; kp < 5; ++kp) { float e = __expf(attn[tid][kp] - mx); attn[tid][kp] = e; sum += e; }
    float inv = 1.f / sum;
    for (int kp = 0; kp < 5; ++kp) attn[tid][kp] *= inv;
  }
  __syncthreads();
  if (tid < 128) {
    int n = tid >> 5;
    float s = 0.f;
    for (int kp = 0; kp < 5; ++kp) s += attn[n][kp] * vbuf[kp][tid];
    ao[tid] = s;
  }
  __syncthreads();
  if (tid < 128) {
    const float* wr = f_wo + (size_t)tid * 128;
    float s = 0.f;
    for (int i = 0; i < 128; ++i) s += ao[i] * wr[i];
    fin[tid] = s + f_bo[tid];
  }
  __syncthreads();
  {
    const float* wr = fc_w + (size_t)tid * 128;
    float s = 0.f;
    for (int j = 0; j < 128; ++j) s += fin[j] * wr[j];
    out[(size_t)b * 192 + tid] = s + fc_b[tid];
  }
}

// ---------------------------------------------------------------------------
extern "C" void kernel_launch(void* const* d_in, const int* in_sizes, int n_in,
                              void* d_out, int out_size, void* d_ws, size_t ws_size,
                              hipStream_t stream)
{
  const float* x      = (const float*)d_in[0];
  const float* w_ih0  = (const float*)d_in[1];
  const float* w_ih12 = (const float*)d_in[2];
  const float* w_hh   = (const float*)d_in[3];
  const float* b_ih   = (const float*)d_in[4];
  const float* b_hh   = (const float*)d_in[5];
  const float* g_wqkv = (const float*)d_in[6];
  const float* g_bqkv = (const float*)d_in[7];
  const float* g_wo   = (const float*)d_in[8];
  const float* g_bo   = (const float*)d_in[9];
  const float* f_wqkv = (const float*)d_in[10];
  const float* f_bqkv = (const float*)d_in[11];
  const float* f_wo   = (const float*)d_in[12];
  const float* f_bo   = (const float*)d_in[13];
  const float* fc_w   = (const float*)d_in[14];
  const float* fc_b   = (const float*)d_in[15];

  const size_t N_hh = (size_t)3 * NFEAT * 512 * 128;
  const size_t N_ih = (size_t)2 * NFEAT * 512 * 128;
  const size_t NB   = (size_t)3 * NFEAT * 512;
  const size_t RSZ  = (size_t)NFEAT * 256 * 4096;   // ring elems (u16)

  u16* Whh       = (u16*)d_ws;
  u16* Wih       = Whh + N_hh;
  float* biasAll = (float*)(Wih + N_ih);
  u16* ring0     = (u16*)(biasAll + NB);
  u16* ring1     = ring0 + RSZ;
  u16* hlast     = ring1 + RSZ;                     // 40*32*128 u16
  int* flags     = (int*)(hlast + (size_t)NFEAT * 32 * 128);  // 192 ints
  float* pooled  = (float*)(flags + 192);           // 32*5*128 f32

  prep_kernel<<<2048, 256, 0, stream>>>(w_ih12, w_hh, b_ih, b_hh,
                                        Whh, Wih, biasAll, flags);

  lstm_fused<<<240, 512, 0, stream>>>(Whh, Wih, biasAll, x, w_ih0,
                                      ring0, ring1, hlast, flags);

  gattn_kernel<<<160, 128, 0, stream>>>(hlast, g_wqkv, g_bqkv, g_wo, g_bo, pooled);
  final_kernel<<<32, 192, 0, stream>>>(pooled, f_wqkv, f_bqkv, f_wo, f_bo,
                                       fc_w, fc_b, (float*)d_out);
}

// Round 8
// 977.846 us; speedup vs baseline: 1.9212x; 1.0819x over previous
//
#include <hip/hip_runtime.h>
#include <cstdint>
#include <cstddef>

// ---------------------------------------------------------------------------
// FeatureWiseCrossAttentionLSTM: F=40, OF=8, OW=24, L=3, H=128, NH=4, G=5
// B=32, T=512.
// R7 on the R6 fused pipeline:
//   - ring h-stores: plain coalesced uint2 (R6 used per-lane atomic u64 —
//     uncoalescable in L2, slow retire). Visibility: stores -> per-step block
//     barrier -> tid0 __threadfence (agent release) -> relaxed flag.
//     Consumer: flag poll -> __threadfence (acquire-inv) -> plain loads.
//   - publish value corrected to T-2 (only those stores are fenced); poll
//     target T+19; sync period 16 steps (was 8).
//   - back-pressure: consumers publish progress; producers throttle at
//     >290-step lead (ring=256) -- closes the overtake hazard.
//   - epilogue 10->7 transcendentals: weights/bias pre-scaled by -log2(e)
//     in prep (exp2-domain gates); c and h each computed as one rational
//     with a single v_rcp.
// ---------------------------------------------------------------------------

#define NFEAT 40
#define TDIM  512

typedef __bf16 bf16x8 __attribute__((ext_vector_type(8)));
typedef float floatx4 __attribute__((ext_vector_type(4)));
typedef float floatx2 __attribute__((ext_vector_type(2)));
typedef int   intx4   __attribute__((ext_vector_type(4)));
typedef unsigned short u16;

#if __has_builtin(__builtin_amdgcn_exp2f)
#define EXP2F __builtin_amdgcn_exp2f
#else
#define EXP2F exp2f
#endif
#if __has_builtin(__builtin_amdgcn_rcpf)
#define RCPF __builtin_amdgcn_rcpf
#else
#define RCPF(x) (1.f / (x))
#endif

#define MF(a, b, c) __builtin_amdgcn_mfma_f32_16x16x32_bf16( \
    __builtin_bit_cast(bf16x8, (a)), __builtin_bit_cast(bf16x8, (b)), (c), 0, 0, 0)

#define NEG_LOG2E -1.44269504f

__device__ __forceinline__ float bf2f(u16 s) {
  union { unsigned u; float f; } v; v.u = ((unsigned)s) << 16; return v.f;
}
__device__ __forceinline__ unsigned f2bf(float f) {
  union { float f; unsigned u; } v; v.f = f;
  unsigned u = v.u + 0x7fffu + ((v.u >> 16) & 1u);
  return (u >> 16);
}

// ring geometry (per layer-boundary): [40][256][32][128] bf16
#define RING_FSTRIDE 1048576   // 256*4096 u16
#define RING_TSTRIDE 4096      // 32*128 u16
#define RING_MASK    255

// ---------------------------------------------------------------------------
// prep: vectorized fp32 -> bf16 weight converts, PRE-SCALED by -log2(e);
// combined pre-scaled bias; zero sync flags.
// ---------------------------------------------------------------------------
__global__ void prep_kernel(const float* __restrict__ w_ih12,
                            const float* __restrict__ w_hh,
                            const float* __restrict__ b_ih,
                            const float* __restrict__ b_hh,
                            u16* __restrict__ Whh,
                            u16* __restrict__ Wih,
                            float* __restrict__ biasAll,
                            int* __restrict__ flags)
{
  const int N_hh4 = 3 * NFEAT * 512 * 128 / 4;   // 1,966,080
  const int N_ih4 = 2 * NFEAT * 512 * 128 / 4;   // 1,310,720
  const int NB    = 3 * NFEAT * 512;             // 61,440
  const int NF    = 384;
  const int total = N_hh4 + N_ih4 + NB + NF;
  for (int idx = blockIdx.x * blockDim.x + threadIdx.x; idx < total;
       idx += gridDim.x * blockDim.x) {
    if (idx < N_hh4 + N_ih4) {
      const bool ih = (idx >= N_hh4);
      const int i4 = (ih ? idx - N_hh4 : idx) * 4;
      const float4 v = *(const float4*)((ih ? w_ih12 : w_hh) + i4);
      uint2 p;
      p.x = (f2bf(v.y * NEG_LOG2E) << 16) | f2bf(v.x * NEG_LOG2E);
      p.y = (f2bf(v.w * NEG_LOG2E) << 16) | f2bf(v.z * NEG_LOG2E);
      *(uint2*)((ih ? Wih : Whh) + i4) = p;
    } else if (idx < N_hh4 + N_ih4 + NB) {
      int i = idx - N_hh4 - N_ih4;
      biasAll[i] = (b_ih[i] + b_hh[i]) * NEG_LOG2E;
    } else {
      flags[idx - N_hh4 - N_ih4 - NB] = 0;
    }
  }
}

// ---------------------------------------------------------------------------
// One layer's recurrence (R4-style step body + ring/flag sync).
// ---------------------------------------------------------------------------
template <int LAYER>
__device__ __forceinline__ void lstm_body(
    const u16* __restrict__ Wh, const u16* __restrict__ Wx,
    const float* __restrict__ bias,
    const float* __restrict__ xin, const float* __restrict__ w0,
    const u16* __restrict__ ringIn, u16* __restrict__ ringOut,
    u16* __restrict__ hlast,
    int* __restrict__ flagIn,       // data-ready flag we poll (consumer side)
    int* __restrict__ flagOut,      // data-ready flag we publish (producer)
    int* __restrict__ flagConsIn,   // downstream progress we read (producer)
    int* __restrict__ flagConsOut,  // our progress we publish (consumer)
    int f, int half, u16* __restrict__ Abase)
{
  constexpr bool IS_L0   = (LAYER == 0);
  constexpr bool IS_LAST = (LAYER == 2);

  const int tid  = threadIdx.x;
  const int wave = tid >> 6;
  const int lane = tid & 63;
  const int m15  = lane & 15;          // batch (B-col / D-col)
  const int q    = lane >> 4;
  const int kb   = q * 8;
  const int wq4  = wave * 16 + q * 4;  // first hidden col owned by lane

#define ALDS(P, M, K) (Abase + ((P) * 16 + (M)) * 136 + (K))

  // ---- resident weight fragments ----
  intx4 whf[4][4];
  const size_t wbase = (size_t)f * 512 * 128;
#pragma unroll
  for (int g = 0; g < 4; ++g)
#pragma unroll
    for (int kt = 0; kt < 4; ++kt)
      whf[g][kt] = *(const intx4*)(Wh + wbase +
          (size_t)(g * 128 + wave * 16 + m15) * 128 + kt * 32 + kb);

  intx4 wxf[4][4];
  if constexpr (!IS_L0) {
#pragma unroll
    for (int g = 0; g < 4; ++g)
#pragma unroll
      for (int kt = 0; kt < 4; ++kt)
        wxf[g][kt] = *(const intx4*)(Wx + wbase +
            (size_t)(g * 128 + wave * 16 + m15) * 128 + kt * 32 + kb);
  }

  floatx4 bv[4], w0v[4];
#pragma unroll
  for (int g = 0; g < 4; ++g) {
    bv[g] = *(const floatx4*)(bias + f * 512 + g * 128 + wq4);
    if constexpr (IS_L0) {
      floatx4 wv = *(const floatx4*)(w0 + f * 512 + g * 128 + wq4);
      w0v[g] = wv * NEG_LOG2E;   // pre-scale rank-1 weights too
    }
  }

  // ---- zero A (h0 = 0) ----
  for (int idx = tid; idx < 2 * 16 * 136; idx += 512) Abase[idx] = 0;

  // ---- initial gate: need x_0..x_18 before priming + first 16 steps ----
  if constexpr (LAYER >= 1) {
    if (tid == 0) {
      while (__hip_atomic_load(flagIn, __ATOMIC_RELAXED,
                               __HIP_MEMORY_SCOPE_AGENT) < 19)
        __builtin_amdgcn_s_sleep(2);
      __threadfence();
    }
  }
  __syncthreads();

  // ---- prime x pipeline ----
  const u16* xbase = (LAYER >= 1)
      ? ringIn + (size_t)f * RING_FSTRIDE + (half * 16 + m15) * 128 + kb
      : nullptr;
  const float* xsbase = IS_L0
      ? xin + ((size_t)(half * 16 + m15) * NFEAT + f) * 512
      : nullptr;

  floatx4 accx0[4], accx1[4];
  intx4 xf0[4], xf1[4];
  float xsc[2] = {0.f, 0.f};

  if constexpr (!IS_L0) {
    intx4 p0[4];
#pragma unroll
    for (int kt = 0; kt < 4; ++kt) p0[kt]  = *(const intx4*)(xbase + kt * 32);
#pragma unroll
    for (int kt = 0; kt < 4; ++kt)
      xf0[kt] = *(const intx4*)(xbase + 1 * RING_TSTRIDE + kt * 32);
#pragma unroll
    for (int kt = 0; kt < 4; ++kt)
      xf1[kt] = *(const intx4*)(xbase + 2 * RING_TSTRIDE + kt * 32);
#pragma unroll
    for (int g = 0; g < 4; ++g) {
      floatx4 a = bv[g];
#pragma unroll
      for (int kt = 0; kt < 4; ++kt) a = MF(wxf[g][kt], p0[kt], a);
      accx0[g] = a;
    }
  } else {
    const float x0 = xsbase[0];
    xsc[0] = xsbase[1];
    xsc[1] = xsbase[2];
#pragma unroll
    for (int g = 0; g < 4; ++g) accx0[g] = bv[g] + w0v[g] * x0;
  }

  float creg[4] = {0.f, 0.f, 0.f, 0.f};
  u16* hb_ring = (LAYER <= 1)
      ? ringOut + (size_t)f * RING_FSTRIDE + (half * 16 + m15) * 128 + wq4
      : nullptr;
  uint2 hdef;

#define LSTM_STEP(PC, ACC_C, ACC_N, XF_C, T)                                   \
  {                                                                            \
    /* sync block: once per 16 steps */                                        \
    if (((T) & 15) == 0 && (T) > 0) {                                          \
      if (tid == 0) {                                                          \
        if constexpr (LAYER >= 1) {                                            \
          int tgt = (T) + 19; if (tgt > 512) tgt = 512;                        \
          while (__hip_atomic_load(flagIn, __ATOMIC_RELAXED,                   \
                                   __HIP_MEMORY_SCOPE_AGENT) < tgt)            \
            __builtin_amdgcn_s_sleep(2);                                       \
        }                                                                      \
        if constexpr (LAYER <= 1) {                                            \
          /* back-pressure: never lap the 256-deep ring */                     \
          while (__hip_atomic_load(flagConsIn, __ATOMIC_RELAXED,               \
                                   __HIP_MEMORY_SCOPE_AGENT) < (T) - 290)      \
            __builtin_amdgcn_s_sleep(2);                                       \
        }                                                                      \
        __threadfence();  /* release our h-stores / acquire polled data */     \
        if constexpr (LAYER <= 1)                                              \
          __hip_atomic_store(flagOut, (T) - 2, __ATOMIC_RELAXED,               \
                             __HIP_MEMORY_SCOPE_AGENT);                        \
        if constexpr (LAYER >= 1)                                              \
          __hip_atomic_store(flagConsOut, (T), __ATOMIC_RELAXED,               \
                             __HIP_MEMORY_SCOPE_AGENT);                        \
      }                                                                        \
      if constexpr (LAYER >= 1) __syncthreads();                               \
    }                                                                          \
    /* deferred (aged) plain h-store of h_{T-1} */                             \
    if constexpr (!IS_LAST) {                                                  \
      if ((T) > 0)                                                             \
        *(uint2*)(hb_ring + (size_t)(((T) - 1) & RING_MASK) * RING_TSTRIDE) =  \
            hdef;                                                              \
    }                                                                          \
    /* x prefetch for t+3 into temps */                                        \
    intx4 xn0, xn1, xn2, xn3;                                                  \
    float xns = 0.f;                                                           \
    {                                                                          \
      const int tl = ((T) + 3 < TDIM) ? (T) + 3 : TDIM - 1;                    \
      if constexpr (!IS_L0) {                                                  \
        const u16* xp = xbase + (size_t)(tl & RING_MASK) * RING_TSTRIDE;       \
        xn0 = *(const intx4*)(xp);                                             \
        xn1 = *(const intx4*)(xp + 32);                                        \
        xn2 = *(const intx4*)(xp + 64);                                        \
        xn3 = *(const intx4*)(xp + 96);                                        \
      } else {                                                                 \
        xns = xsbase[tl];                                                      \
      }                                                                        \
    }                                                                          \
    /* h fragments from LDS */                                                 \
    intx4 hf0 = *(const intx4*)ALDS(PC, m15, kb);                              \
    intx4 hf1 = *(const intx4*)ALDS(PC, m15, 32 + kb);                         \
    intx4 hf2 = *(const intx4*)ALDS(PC, m15, 64 + kb);                         \
    intx4 hf3 = *(const intx4*)ALDS(PC, m15, 96 + kb);                         \
    /* h-MFMA (critical path) */                                               \
    floatx4 ac0 = MF(whf[0][0], hf0, ACC_C[0]);                                \
    floatx4 ac1 = MF(whf[1][0], hf0, ACC_C[1]);                                \
    floatx4 ac2 = MF(whf[2][0], hf0, ACC_C[2]);                                \
    floatx4 ac3 = MF(whf[3][0], hf0, ACC_C[3]);                                \
    ac0 = MF(whf[0][1], hf1, ac0); ac1 = MF(whf[1][1], hf1, ac1);              \
    ac2 = MF(whf[2][1], hf1, ac2); ac3 = MF(whf[3][1], hf1, ac3);              \
    ac0 = MF(whf[0][2], hf2, ac0); ac1 = MF(whf[1][2], hf2, ac1);              \
    ac2 = MF(whf[2][2], hf2, ac2); ac3 = MF(whf[3][2], hf2, ac3);              \
    ac0 = MF(whf[0][3], hf3, ac0); ac1 = MF(whf[1][3], hf3, ac1);              \
    ac2 = MF(whf[2][3], hf3, ac2); ac3 = MF(whf[3][3], hf3, ac3);              \
    /* x-group: NEXT step's C-init (off critical path), then rotate */         \
    if constexpr (!IS_L0) {                                                    \
      floatx4 n0 = bv[0], n1 = bv[1], n2 = bv[2], n3 = bv[3];                  \
      n0 = MF(wxf[0][0], XF_C[0], n0); n1 = MF(wxf[1][0], XF_C[0], n1);        \
      n2 = MF(wxf[2][0], XF_C[0], n2); n3 = MF(wxf[3][0], XF_C[0], n3);        \
      n0 = MF(wxf[0][1], XF_C[1], n0); n1 = MF(wxf[1][1], XF_C[1], n1);        \
      n2 = MF(wxf[2][1], XF_C[1], n2); n3 = MF(wxf[3][1], XF_C[1], n3);        \
      n0 = MF(wxf[0][2], XF_C[2], n0); n1 = MF(wxf[1][2], XF_C[2], n1);        \
      n2 = MF(wxf[2][2], XF_C[2], n2); n3 = MF(wxf[3][2], XF_C[2], n3);        \
      n0 = MF(wxf[0][3], XF_C[3], n0); n1 = MF(wxf[1][3], XF_C[3], n1);        \
      n2 = MF(wxf[2][3], XF_C[3], n2); n3 = MF(wxf[3][3], XF_C[3], n3);        \
      ACC_N[0] = n0; ACC_N[1] = n1; ACC_N[2] = n2; ACC_N[3] = n3;              \
      XF_C[0] = xn0; XF_C[1] = xn1; XF_C[2] = xn2; XF_C[3] = xn3;              \
    } else {                                                                   \
      const float xn = xsc[PC];                                                \
      ACC_N[0] = bv[0] + w0v[0] * xn; ACC_N[1] = bv[1] + w0v[1] * xn;          \
      ACC_N[2] = bv[2] + w0v[2] * xn; ACC_N[3] = bv[3] + w0v[3] * xn;          \
      xsc[PC] = xns;                                                           \
    }                                                                          \
    /* epilogue (exp2-domain gates): 5 exp2 + 2 rcp per element */             \
    unsigned hlo, hhi;                                                         \
    {                                                                          \
      float hv[4];                                                             \
      _Pragma("unroll")                                                        \
      for (int r = 0; r < 4; ++r) {                                            \
        const float Ei = EXP2F(ac0[r]);                                        \
        const float Ef = EXP2F(ac1[r]);                                        \
        const float Eg = EXP2F(2.f * ac2[r]);                                  \
        const float Eo = EXP2F(ac3[r]);                                        \
        const float Pp = (1.f + Ei) * (1.f + Eg);                              \
        const float Qq = 1.f + Ef;                                             \
        const float c  = (creg[r] * Pp + Qq * (1.f - Eg)) * RCPF(Qq * Pp);     \
        creg[r] = c;                                                           \
        const float Ec = EXP2F(-2.88539008f * c);                              \
        hv[r] = (1.f - Ec) * RCPF((1.f + Ec) * (1.f + Eo));                    \
      }                                                                        \
      hlo = (f2bf(hv[1]) << 16) | f2bf(hv[0]);                                 \
      hhi = (f2bf(hv[3]) << 16) | f2bf(hv[2]);                                 \
    }                                                                          \
    uint2 hp; hp.x = hlo; hp.y = hhi;                                          \
    *(uint2*)ALDS((PC) ^ 1, m15, wq4) = hp;                                    \
    hdef = hp;                                                                 \
    __syncthreads();                                                           \
  }

#pragma unroll 1
  for (int t = 0; t < TDIM; t += 2) {
    LSTM_STEP(0, accx0, accx1, xf0, t);
    LSTM_STEP(1, accx1, accx0, xf1, t + 1);
  }
#undef LSTM_STEP
#undef ALDS

  // ---- tail: final h (t=511) ----
  if constexpr (!IS_LAST) {
    *(uint2*)(hb_ring + (size_t)(511 & RING_MASK) * RING_TSTRIDE) = hdef;
    __syncthreads();   // all waves' stores happen-before tid0's fence
    if (tid == 0) {
      __threadfence();
      __hip_atomic_store(flagOut, 512, __ATOMIC_RELAXED,
                         __HIP_MEMORY_SCOPE_AGENT);
    }
  } else {
    *(uint2*)(hlast + ((size_t)f * 32 + half * 16 + m15) * 128 + wq4) = hdef;
  }
}

// ---------------------------------------------------------------------------
// Fused 3-layer LSTM: 240 blocks (80 per layer), all co-resident.
// flags: [0..79] ready0, [80..159] ready1, [160..239] cons0, [240..319] cons1
// ---------------------------------------------------------------------------
__global__ __launch_bounds__(512, 2) void lstm_fused(
    const u16* __restrict__ Whh, const u16* __restrict__ Wih,
    const float* __restrict__ biasAll,
    const float* __restrict__ xin, const float* __restrict__ w0,
    u16* __restrict__ ring0, u16* __restrict__ ring1,
    u16* __restrict__ hlast, int* __restrict__ flags)
{
  __shared__ __align__(16) u16 A[2 * 16 * 136];
  const int layer = blockIdx.x / 80;
  const int bx    = blockIdx.x % 80;
  const int f = bx >> 1, half = bx & 1;
  const size_t LSL = (size_t)NFEAT * 512 * 128;

  if (layer == 0) {
    lstm_body<0>(Whh, nullptr, biasAll, xin, w0,
                 nullptr, ring0, nullptr,
                 nullptr, flags + bx, flags + 160 + bx, nullptr,
                 f, half, A);
  } else if (layer == 1) {
    lstm_body<1>(Whh + LSL, Wih, biasAll + NFEAT * 512, nullptr, nullptr,
                 ring0, ring1, nullptr,
                 flags + bx, flags + 80 + bx, flags + 240 + bx,
                 flags + 160 + bx, f, half, A);
  } else {
    lstm_body<2>(Whh + 2 * LSL, Wih + LSL, biasAll + 2 * NFEAT * 512,
                 nullptr, nullptr, ring1, nullptr, hlast,
                 flags + 80 + bx, nullptr, nullptr, flags + 240 + bx,
                 f, half, A);
  }
}

// ---------------------------------------------------------------------------
// Group attention: grid (G=5 x B=32) blocks, 128 threads.
// ---------------------------------------------------------------------------
__global__ void gattn_kernel(const u16* __restrict__ hlast,
                             const float* __restrict__ g_wqkv,
                             const float* __restrict__ g_bqkv,
                             const float* __restrict__ g_wo,
                             const float* __restrict__ g_bo,
                             float* __restrict__ pooled)
{
  const int tid = threadIdx.x;
  const int g = blockIdx.x >> 5;
  const int b = blockIdx.x & 31;

  __shared__ float feat[8][128];
  __shared__ float qkv[8][384];
  __shared__ float sc[4][8][8];
  __shared__ float colsum[4][8];
  __shared__ float poolin[128];

  for (int idx = tid; idx < 8 * 128; idx += 128) {
    int of = idx >> 7, j = idx & 127;
    int f = g * 8 + of;
    feat[of][j] = bf2f(hlast[((size_t)f * 32 + b) * 128 + j]);
  }
  __syncthreads();
  for (int idx = tid; idx < 8 * 384; idx += 128) {
    int of = idx / 384, r = idx - of * 384;
    const float* wr = g_wqkv + ((size_t)g * 384 + r) * 128;
    float s = 0.f;
    for (int j = 0; j < 128; ++j) s += feat[of][j] * wr[j];
    qkv[of][r] = s + g_bqkv[g * 384 + r];
  }
  __syncthreads();
  for (int idx = tid; idx < 256; idx += 128) {
    int n = idx >> 6, qp = (idx >> 3) & 7, kp = idx & 7;
    float s = 0.f;
    for (int d = 0; d < 32; ++d)
      s += qkv[qp][n * 32 + d] * qkv[kp][128 + n * 32 + d];
    sc[n][qp][kp] = s * 0.17677669529663687f;
  }
  __syncthreads();
  if (tid < 32) {
    int n = tid >> 3, qp = tid & 7;
    float mx = -1e30f;
    for (int kp = 0; kp < 8; ++kp) mx = fmaxf(mx, sc[n][qp][kp]);
    float e[8], sum = 0.f;
    for (int kp = 0; kp < 8; ++kp) { e[kp] = __expf(sc[n][qp][kp] - mx); sum += e[kp]; }
    float inv = 1.f / sum;
    for (int kp = 0; kp < 8; ++kp) sc[n][qp][kp] = e[kp] * inv;
  }
  __syncthreads();
  if (tid < 32) {
    int n = tid >> 3, kp = tid & 7;
    float s = 0.f;
    for (int qp = 0; qp < 8; ++qp) s += sc[n][qp][kp];
    colsum[n][kp] = s;
  }
  __syncthreads();
  {
    int n = tid >> 5;
    float s = 0.f;
    for (int kp = 0; kp < 8; ++kp) s += colsum[n][kp] * qkv[kp][256 + tid];
    poolin[tid] = s;
  }
  __syncthreads();
  {
    const float* wr = g_wo + ((size_t)g * 128 + tid) * 128;
    float s = 0.f;
    for (int i = 0; i < 128; ++i) s += poolin[i] * wr[i];
    pooled[((size_t)b * 5 + g) * 128 + tid] = s * 0.125f + g_bo[g * 128 + tid];
  }
}

// ---------------------------------------------------------------------------
// Final attention (query pos 0 only) + FC. Grid: 32 blocks, 192 threads.
// ---------------------------------------------------------------------------
__global__ void final_kernel(const float* __restrict__ pooled,
                             const float* __restrict__ f_wqkv,
                             const float* __restrict__ f_bqkv,
                             const float* __restrict__ f_wo,
                             const float* __restrict__ f_bo,
                             const float* __restrict__ fc_w,
                             const float* __restrict__ fc_b,
                             float* __restrict__ out)
{
  const int tid = threadIdx.x;
  const int b = blockIdx.x;

  __shared__ float P[5][128];
  __shared__ float q0[128];
  __shared__ float kbuf[5][128];
  __shared__ float vbuf[5][128];
  __shared__ float attn[4][5];
  __shared__ float ao[128];
  __shared__ float fin[128];

  for (int idx = tid; idx < 640; idx += 192) {
    int g = idx >> 7, j = idx & 127;
    P[g][j] = pooled[((size_t)b * 5 + g) * 128 + j];
  }
  __syncthreads();
  for (int idx = tid; idx < 1408; idx += 192) {
    int kind, pos, r;
    if (idx < 128)       { kind = 0; pos = 0;                 r = idx; }
    else if (idx < 768)  { kind = 1; pos = (idx - 128) >> 7;  r = (idx - 128) & 127; }
    else                 { kind = 2; pos = (idx - 768) >> 7;  r = (idx - 768) & 127; }
    const int wrow = kind * 128 + r;
    const float* wr = f_wqkv + (size_t)wrow * 128;
    const float* src = P[kind == 0 ? 0 : pos];
    float s = 0.f;
    for (int j = 0; j < 128; ++j) s += src[j] * wr[j];
    s += f_bqkv[wrow];
    if (kind == 0) q0[r] = s;
    else if (kind == 1) kbuf[pos][r] = s;
    else vbuf[pos][r] = s;
  }
  __syncthreads();
  if (tid < 20) {
    int n = tid / 5, kp = tid - n * 5;
    float s = 0.f;
    for (int d = 0; d < 32; ++d) s += q0[n * 32 + d] * kbuf[kp][n * 32 + d];
    attn[n][kp] = s * 0.17677669529663687f;
  }
  __syncthreads();
  if (tid < 4) {
    float mx = -1e30f;
    for (int kp = 0; kp < 5; ++kp) mx = fmaxf(mx, attn[tid][kp]);
    float sum = 0.f;
    for (int kp = 0; kp < 5; ++kp) { float e = __expf(attn[tid][kp] - mx); attn[tid][kp] = e; sum += e; }
    float inv = 1.f / sum;
    for (int kp = 0; kp < 5; ++kp) attn[tid][kp] *= inv;
  }
  __syncthreads();
  if (tid < 128) {
    int n = tid >> 5;
    float s = 0.f;
    for (int kp = 0; kp < 5; ++kp) s += attn[n][kp] * vbuf[kp][tid];
    ao[tid] = s;
  }
  __syncthreads();
  if (tid < 128) {
    const float* wr = f_wo + (size_t)tid * 128;
    float s = 0.f;
    for (int i = 0; i < 128; ++i) s += ao[i] * wr[i];
    fin[tid] = s + f_bo[tid];
  }
  __syncthreads();
  {
    const float* wr = fc_w + (size_t)tid * 128;
    float s = 0.f;
    for (int j = 0; j < 128; ++j) s += fin[j] * wr[j];
    out[(size_t)b * 192 + tid] = s + fc_b[tid];
  }
}

// ---------------------------------------------------------------------------
extern "C" void kernel_launch(void* const* d_in, const int* in_sizes, int n_in,
                              void* d_out, int out_size, void* d_ws, size_t ws_size,
                              hipStream_t stream)
{
  const float* x      = (const float*)d_in[0];
  const float* w_ih0  = (const float*)d_in[1];
  const float* w_ih12 = (const float*)d_in[2];
  const float* w_hh   = (const float*)d_in[3];
  const float* b_ih   = (const float*)d_in[4];
  const float* b_hh   = (const float*)d_in[5];
  const float* g_wqkv = (const float*)d_in[6];
  const float* g_bqkv = (const float*)d_in[7];
  const float* g_wo   = (const float*)d_in[8];
  const float* g_bo   = (const float*)d_in[9];
  const float* f_wqkv = (const float*)d_in[10];
  const float* f_bqkv = (const float*)d_in[11];
  const float* f_wo   = (const float*)d_in[12];
  const float* f_bo   = (const float*)d_in[13];
  const float* fc_w   = (const float*)d_in[14];
  const float* fc_b   = (const float*)d_in[15];

  const size_t N_hh = (size_t)3 * NFEAT * 512 * 128;
  const size_t N_ih = (size_t)2 * NFEAT * 512 * 128;
  const size_t NB   = (size_t)3 * NFEAT * 512;
  const size_t RSZ  = (size_t)NFEAT * 256 * 4096;   // ring elems (u16)

  u16* Whh       = (u16*)d_ws;
  u16* Wih       = Whh + N_hh;
  float* biasAll = (float*)(Wih + N_ih);
  u16* ring0     = (u16*)(biasAll + NB);
  u16* ring1     = ring0 + RSZ;
  u16* hlast     = ring1 + RSZ;                     // 40*32*128 u16
  int* flags     = (int*)(hlast + (size_t)NFEAT * 32 * 128);  // 384 ints
  float* pooled  = (float*)(flags + 384);           // 32*5*128 f32

  prep_kernel<<<4096, 256, 0, stream>>>(w_ih12, w_hh, b_ih, b_hh,
                                        Whh, Wih, biasAll, flags);

  lstm_fused<<<240, 512, 0, stream>>>(Whh, Wih, biasAll, x, w_ih0,
                                      ring0, ring1, hlast, flags);

  gattn_kernel<<<160, 128, 0, stream>>>(hlast, g_wqkv, g_bqkv, g_wo, g_bo, pooled);
  final_kernel<<<32, 192, 0, stream>>>(pooled, f_wqkv, f_bqkv, f_wo, f_bo,
                                       fc_w, fc_b, (float*)d_out);
}